// Round 6
// baseline (671.993 us; speedup 1.0000x reference)
//
#include <hip/hip_runtime.h>
#include <math.h>

#define N_NODES 50000
#define N_EDGES 800000

typedef short bf8 __attribute__((ext_vector_type(8)));    // 8 bf16 (A/B frag)
typedef float f4x __attribute__((ext_vector_type(4)));    // C/D frag
typedef float f2v __attribute__((ext_vector_type(2)));    // packed fp32
typedef unsigned short us8 __attribute__((ext_vector_type(8)));  // 16B bf16

__device__ __forceinline__ unsigned short f2bf(float x) {
  unsigned u = __float_as_uint(x);
  unsigned r = (u + 0x7fff + ((u >> 16) & 1)) >> 16;  // RNE
  return (unsigned short)r;
}
__device__ __forceinline__ float bf2f(unsigned short b) {
  return __uint_as_float(((unsigned)b) << 16);
}
__device__ __forceinline__ f2v bfpair(unsigned d) {
  f2v r;
  r.x = __uint_as_float(d << 16);
  r.y = __uint_as_float(d & 0xffff0000u);
  return r;
}

// ---------------------------------------------------------------------------
// SLICED feature layout: tables are stored [n_slices][N][32] bf16 (64B/row
// slice). Gather blocks pin slice = bid & (NS-1); with round-robin block->XCD
// dispatch this makes each XCD gather from a 3.2MB slice that FITS its 4MB
// private L2 (vs 25.6MB table -> ~0% L2 hit, 198MB LLC traffic in R5).
// ---------------------------------------------------------------------------

// One-shot conversions, single dispatch:
//   region 0: feat fp32 -> bf16 SLICED [4][N][32]
//   regions 1-3: W[K][M] fp32 -> WT[M][K] bf16 (transpose)
__device__ __forceinline__ void wt_cvt_one(const float* __restrict__ W,
                                           unsigned short* __restrict__ WT,
                                           int K, int M, int j) {
  int k8n = K >> 3;
  int m = j / k8n, k8 = j - m * k8n;
  us8 o;
#pragma unroll
  for (int r = 0; r < 8; ++r) o[r] = f2bf(W[(size_t)(k8 * 8 + r) * M + m]);
  *(us8*)(WT + (size_t)m * K + k8 * 8) = o;
}

__global__ __launch_bounds__(256) void cvt_all_k(
    const float* __restrict__ feat, unsigned short* __restrict__ featb,
    const float* __restrict__ W1, unsigned short* __restrict__ wt1,
    const float* __restrict__ W2, unsigned short* __restrict__ wt2,
    const float* __restrict__ W3, unsigned short* __restrict__ wt3) {
  const int F8 = N_NODES * 128 / 8;  // 800000
  int i = blockIdx.x * 256 + threadIdx.x;
  if (i < F8) {
    int n = i >> 4, c8 = i & 15;  // row, 8-col chunk
    float4 a = ((const float4*)feat)[2 * i];
    float4 b = ((const float4*)feat)[2 * i + 1];
    us8 o;
    o[0] = f2bf(a.x); o[1] = f2bf(a.y); o[2] = f2bf(a.z); o[3] = f2bf(a.w);
    o[4] = f2bf(b.x); o[5] = f2bf(b.y); o[6] = f2bf(b.z); o[7] = f2bf(b.w);
    // sliced: slice = c8>>2, in-slice offset (c8&3)*8
    *(us8*)(featb + ((size_t)(c8 >> 2) * N_NODES + n) * 32 + (c8 & 3) * 8) = o;
    return;
  }
  int j = i - F8;
  if (j < 4096) {                    // W1: 256 x 128
    wt_cvt_one(W1, wt1, 128, 256, j);
    return;
  }
  j -= 4096;
  if (j < 8192) {                    // W2: 256 x 256
    wt_cvt_one(W2, wt2, 256, 256, j);
    return;
  }
  j -= 8192;
  if (j < 2048) {                    // W3: 64 x 256
    wt_cvt_one(W3, wt3, 256, 64, j);
  }
}

// ---------------------------------------------------------------------------
// MFMA GEMM + fused el/er epilogue. Full-width output block (BN = M); A is
// read once. A input and Y output both in SLICED [c][N][32] layout.
// BM=64, BK=32, 256 thr = 4 waves; wave owns 16-row stripe x M cols.
// ---------------------------------------------------------------------------
template <int NCT>
__global__ __launch_bounds__(256) void gemm_mfma_k(
    const unsigned short* __restrict__ Xb,
    const unsigned short* __restrict__ WT, unsigned short* __restrict__ Yb,
    float* __restrict__ el, float* __restrict__ er,
    const float* __restrict__ al, const float* __restrict__ ar, int N,
    int K) {
  const int H = NCT >> 2;  // heads (64 cols each)
  __shared__ unsigned short As[64][40];        // [m][k], +8 pad
  __shared__ unsigned short Bs[NCT * 16][40];  // [n][k], +8 pad
  const int tile_n = blockIdx.x * 64;
  const int t = threadIdx.x;
  const int wave = t >> 6, lane = t & 63;
  const int quad = lane >> 4, l16 = lane & 15;

  f4x acc[NCT];
#pragma unroll
  for (int ct = 0; ct < NCT; ++ct) acc[ct] = (f4x){0.f, 0.f, 0.f, 0.f};

  const int arow = t >> 2;         // A row 0..63
  const int akoff = (t & 3) * 8;   // A k-oct within 32-col slice

  for (int k0 = 0; k0 < K; k0 += 32) {
    {
      int gr = tile_n + arow;
      us8 a = (us8)0;
      if (gr < N)
        a = *(const us8*)(Xb + ((size_t)(k0 >> 5) * N + gr) * 32 + akoff);
      *(us8*)&As[arow][akoff] = a;
    }
#pragma unroll
    for (int u = 0; u < NCT / 4; ++u) {
      int g = t + u * 256;
      int brow = g >> 2, bk = (g & 3) * 8;
      *(us8*)&Bs[brow][bk] = *(const us8*)(WT + (size_t)brow * K + k0 + bk);
    }
    __syncthreads();
    bf8 afrag = *(const bf8*)&As[wave * 16 + l16][quad * 8];
#pragma unroll
    for (int ct = 0; ct < NCT; ++ct) {
      bf8 bfrag = *(const bf8*)&Bs[ct * 16 + l16][quad * 8];
      acc[ct] = __builtin_amdgcn_mfma_f32_16x16x32_bf16(afrag, bfrag, acc[ct],
                                                        0, 0, 0);
    }
    __syncthreads();
  }
  float al4[NCT], ar4[NCT];
#pragma unroll
  for (int ct = 0; ct < NCT; ++ct) {
    al4[ct] = al[ct * 16 + l16];
    ar4[ct] = ar[ct * 16 + l16];
  }
#pragma unroll
  for (int r = 0; r < 4; ++r) {
    int row = tile_n + wave * 16 + quad * 4 + r;
    float pl[H], pr[H];
#pragma unroll
    for (int h = 0; h < H; ++h) {
      pl[h] = 0.f;
      pr[h] = 0.f;
    }
#pragma unroll
    for (int ct = 0; ct < NCT; ++ct) {
      float y = acc[ct][r];
      pl[ct >> 2] += y * al4[ct];
      pr[ct >> 2] += y * ar4[ct];
      if (row < N)  // sliced write: slice ct>>1, in-slice col (ct&1)*16+l16
        Yb[((size_t)(ct >> 1) * N + row) * 32 + (ct & 1) * 16 + l16] = f2bf(y);
    }
#pragma unroll
    for (int off = 1; off < 16; off <<= 1)
#pragma unroll
      for (int h = 0; h < H; ++h) {
        pl[h] += __shfl_xor(pl[h], off);
        pr[h] += __shfl_xor(pr[h], off);
      }
    if (l16 == 0 && row < N) {
#pragma unroll
      for (int h = 0; h < H; ++h) {
        el[row * H + h] = pl[h];
        er[row * H + h] = pr[h];
      }
    }
  }
}

// ---------------------------------------------------------------------------
// CSR build (4 edges per thread, int4 loads)
// ---------------------------------------------------------------------------
__global__ __launch_bounds__(256) void count_deg_k(
    const int4* __restrict__ dst4, int* __restrict__ deg, int E4) {
  int i = blockIdx.x * blockDim.x + threadIdx.x;
  if (i < E4) {
    int4 d = dst4[i];
    atomicAdd(&deg[d.x], 1);
    atomicAdd(&deg[d.y], 1);
    atomicAdd(&deg[d.z], 1);
    atomicAdd(&deg[d.w], 1);
  }
}

__global__ __launch_bounds__(256) void alloc_rows_k(
    const int* __restrict__ deg, int* __restrict__ rowstart,
    int* __restrict__ cursor, int* __restrict__ gcounter, int N) {
  int i = blockIdx.x * blockDim.x + threadIdx.x;
  int lane = threadIdx.x & 63;
  int d = (i < N) ? deg[i] : 0;
  int x = d;
#pragma unroll
  for (int off = 1; off < 64; off <<= 1) {
    int t = __shfl_up(x, off);
    if (lane >= off) x += t;
  }
  int wsum = __shfl(x, 63);
  int base = 0;
  if (lane == 63) base = atomicAdd(gcounter, wsum);
  base = __shfl(base, 63);
  if (i < N) {
    int mystart = base + x - d;
    rowstart[i] = mystart;
    cursor[i] = mystart;
  }
}

__global__ __launch_bounds__(256) void scatter_k(
    const int4* __restrict__ src4, const int4* __restrict__ dst4,
    int* __restrict__ cursor, int* __restrict__ src_sorted, int E4) {
  int i = blockIdx.x * blockDim.x + threadIdx.x;
  if (i < E4) {
    int4 s = src4[i];
    int4 d = dst4[i];
    int p0 = atomicAdd(&cursor[d.x], 1);
    src_sorted[p0] = s.x;
    int p1 = atomicAdd(&cursor[d.y], 1);
    src_sorted[p1] = s.y;
    int p2 = atomicAdd(&cursor[d.z], 1);
    src_sorted[p2] = s.z;
    int p3 = atomicAdd(&cursor[d.w], 1);
    src_sorted[p3] = s.w;
  }
}

// ---------------------------------------------------------------------------
// XCD-sliced single-pass softmax+aggregation, H=4. One wave per (node,slice).
// slice = bid & 7 == XCD (round-robin dispatch) -> per-XCD gather working set
// = 3.2MB slice, L2-resident. Phase A: 64 edges wave-wide, exp for this
// slice's head. Phase B: 16 edges/instr x 64B (4 lanes x 16B).
// ---------------------------------------------------------------------------
template <int RELU>
__global__ __launch_bounds__(256) void node_agg4s_k(
    const unsigned short* __restrict__ hb, const float* __restrict__ el,
    const float* __restrict__ er, const int* __restrict__ rowstart,
    const int* __restrict__ rowend, const int* __restrict__ src_sorted,
    const float* __restrict__ bias, unsigned short* __restrict__ outb,
    int N) {
  const int bid = blockIdx.x;
  const int slice = bid & 7;
  const int node = (bid >> 3) * 4 + (threadIdx.x >> 6);
  const int lane = threadIdx.x & 63;
  if (node >= N) return;
  const int head = slice >> 1;
  const int flane = lane & 3;   // 4 lanes x 16B = 64B slice row
  const int eslot = lane >> 2;  // 16 edges in flight per phase-B instr
  int start = rowstart[node], end = rowend[node];
  float er_a = er[node * 4 + head];
  f2v acc2[4];
#pragma unroll
  for (int q = 0; q < 4; ++q) acc2[q] = (f2v){0.f, 0.f};
  float ssum = 0.f;
  const unsigned short* hslice = hb + (size_t)slice * N * 32;
  for (int c0 = start; c0 < end; c0 += 64) {
    // phase A: 64 edges wave-wide, this head's exp
    int p = c0 + lane;
    bool v = p < end;
    int s = v ? src_sorted[p] : 0;
    float e = el[s * 4 + head] + er_a;
    e = (e >= 0.f) ? e : 0.2f * e;
    float ex = v ? __expf(e) : 0.f;
    ssum += ex;
    // phase B: 16 edges x 64B per instruction
    int nch = end - c0;
    if (nch > 64) nch = 64;
    int nj = (nch + 15) >> 4;  // wave-uniform, 1..4
#pragma unroll 4
    for (int jj = 0; jj < nj; ++jj) {
      int idx = jj * 16 + eslot;
      int sj = __shfl(s, idx);
      float aj = __shfl(ex, idx);
      uint4 d = *(const uint4*)(hslice + (size_t)sj * 32 + flane * 8);
      f2v a2 = (f2v){aj, aj};
      acc2[0] += bfpair(d.x) * a2;
      acc2[1] += bfpair(d.y) * a2;
      acc2[2] += bfpair(d.z) * a2;
      acc2[3] += bfpair(d.w) * a2;
    }
  }
  // denominator: all lanes same head -> full reduce
#pragma unroll
  for (int off = 1; off < 64; off <<= 1) ssum += __shfl_xor(ssum, off);
  float acc[8];
#pragma unroll
  for (int q = 0; q < 4; ++q) {
    acc[2 * q] = acc2[q].x;
    acc[2 * q + 1] = acc2[q].y;
  }
  // combine edge slots (xor 4..32 preserves flane)
#pragma unroll
  for (int off = 4; off < 64; off <<= 1)
#pragma unroll
    for (int q = 0; q < 8; ++q) acc[q] += __shfl_xor(acc[q], off);
  float inv = (end > start) ? 1.f / ssum : 0.f;
  if (eslot == 0) {
    us8 o;
#pragma unroll
    for (int q = 0; q < 8; ++q) {
      float vv = acc[q] * inv + bias[slice * 32 + flane * 8 + q];
      if (RELU) vv = fmaxf(vv, 0.f);
      o[q] = f2bf(vv);
    }
    *(us8*)(outb + ((size_t)slice * N + node) * 32 + flane * 8) = o;
  }
}

// H=1, F=64, fp32 out: 2 slices (even/odd XCDs each cache a 3.2MB slice).
__global__ __launch_bounds__(256) void node_agg1s_k(
    const unsigned short* __restrict__ hb, const float* __restrict__ el,
    const float* __restrict__ er, const int* __restrict__ rowstart,
    const int* __restrict__ rowend, const int* __restrict__ src_sorted,
    const float* __restrict__ bias, float* __restrict__ out, int N) {
  const int bid = blockIdx.x;
  const int slice = bid & 1;
  const int node = (bid >> 1) * 4 + (threadIdx.x >> 6);
  const int lane = threadIdx.x & 63;
  if (node >= N) return;
  const int flane = lane & 3;
  const int eslot = lane >> 2;
  int start = rowstart[node], end = rowend[node];
  float er_v = er[node];
  f2v acc2[4];
#pragma unroll
  for (int q = 0; q < 4; ++q) acc2[q] = (f2v){0.f, 0.f};
  float ssum = 0.f;
  const unsigned short* hslice = hb + (size_t)slice * N * 32;
  for (int c0 = start; c0 < end; c0 += 64) {
    int p = c0 + lane;
    bool v = p < end;
    int s = v ? src_sorted[p] : 0;
    float e = el[s] + er_v;
    e = (e >= 0.f) ? e : 0.2f * e;
    float ex = v ? __expf(e) : 0.f;
    ssum += ex;
    int nch = end - c0;
    if (nch > 64) nch = 64;
    int nj = (nch + 15) >> 4;
#pragma unroll 4
    for (int jj = 0; jj < nj; ++jj) {
      int idx = jj * 16 + eslot;
      int sj = __shfl(s, idx);
      float aj = __shfl(ex, idx);
      uint4 d = *(const uint4*)(hslice + (size_t)sj * 32 + flane * 8);
      f2v a2 = (f2v){aj, aj};
      acc2[0] += bfpair(d.x) * a2;
      acc2[1] += bfpair(d.y) * a2;
      acc2[2] += bfpair(d.z) * a2;
      acc2[3] += bfpair(d.w) * a2;
    }
  }
#pragma unroll
  for (int off = 1; off < 64; off <<= 1) ssum += __shfl_xor(ssum, off);
  float acc[8];
#pragma unroll
  for (int q = 0; q < 4; ++q) {
    acc[2 * q] = acc2[q].x;
    acc[2 * q + 1] = acc2[q].y;
  }
#pragma unroll
  for (int off = 4; off < 64; off <<= 1)
#pragma unroll
    for (int q = 0; q < 8; ++q) acc[q] += __shfl_xor(acc[q], off);
  float inv = (end > start) ? 1.f / ssum : 0.f;
  if (eslot == 0) {
    float* o = out + (size_t)node * 64 + slice * 32 + flane * 8;
    float4 o0, o1;
    o0.x = acc[0] * inv + bias[slice * 32 + flane * 8 + 0];
    o0.y = acc[1] * inv + bias[slice * 32 + flane * 8 + 1];
    o0.z = acc[2] * inv + bias[slice * 32 + flane * 8 + 2];
    o0.w = acc[3] * inv + bias[slice * 32 + flane * 8 + 3];
    o1.x = acc[4] * inv + bias[slice * 32 + flane * 8 + 4];
    o1.y = acc[5] * inv + bias[slice * 32 + flane * 8 + 5];
    o1.z = acc[6] * inv + bias[slice * 32 + flane * 8 + 6];
    o1.w = acc[7] * inv + bias[slice * 32 + flane * 8 + 7];
    *(float4*)(o + 0) = o0;
    *(float4*)(o + 4) = o1;
  }
}

// ---------------------------------------------------------------------------
extern "C" void kernel_launch(void* const* d_in, const int* in_sizes, int n_in,
                              void* d_out, int out_size, void* d_ws,
                              size_t ws_size, hipStream_t stream) {
  const float* feat = (const float*)d_in[0];
  const int* src = (const int*)d_in[1];
  const int* dst = (const int*)d_in[2];
  const float* W1 = (const float*)d_in[3];
  const float* al1 = (const float*)d_in[4];
  const float* ar1 = (const float*)d_in[5];
  const float* b1 = (const float*)d_in[6];
  const float* W2 = (const float*)d_in[7];
  const float* al2 = (const float*)d_in[8];
  const float* ar2 = (const float*)d_in[9];
  const float* b2 = (const float*)d_in[10];
  const float* W3 = (const float*)d_in[11];
  const float* al3 = (const float*)d_in[12];
  const float* ar3 = (const float*)d_in[13];
  const float* b3 = (const float*)d_in[14];
  float* out = (float*)d_out;

  unsigned short* hb = (unsigned short*)d_ws;             // [8][N][32] bf16
  unsigned short* fb = hb + (size_t)N_NODES * 256;        // [8][N][32] bf16
  float* el = (float*)(fb + (size_t)N_NODES * 256);       // N*4
  float* er = el + (size_t)N_NODES * 4;                   // N*4
  int* rowstart = (int*)(er + (size_t)N_NODES * 4);       // N
  int* cursor = rowstart + N_NODES;                       // N
  int* deg = cursor + N_NODES;                            // N
  int* gcounter = deg + N_NODES;                          // 1
  int* src_sorted = gcounter + 1;                         // E
  unsigned short* wt1 = (unsigned short*)(src_sorted + N_EDGES);  // 256*128
  unsigned short* wt2 = wt1 + 256 * 128;                  // 256*256
  unsigned short* wt3 = wt2 + 256 * 256;                  // 64*256
  // featb (sliced bf16 feat) aliases fb: GEMM1 consumes it before agg writes.
  unsigned short* featb = fb;

  const int N = N_NODES, E = N_EDGES;
  const int E4 = E / 4;
  const int GX = (N + 63) / 64;  // 782
  const int NB4 = ((N + 3) / 4);  // node-groups of 4

  // ---- one-shot conversions (single dispatch) ----
  const int CVT_TOTAL = N * 128 / 8 + 4096 + 8192 + 2048;
  hipLaunchKernelGGL(cvt_all_k, dim3((CVT_TOTAL + 255) / 256), dim3(256), 0,
                     stream, feat, featb, W1, wt1, W2, wt2, W3, wt3);

  // ---- CSR build ----
  hipMemsetAsync(deg, 0, (size_t)(N + 1) * sizeof(int), stream);
  hipLaunchKernelGGL(count_deg_k, dim3((E4 + 255) / 256), dim3(256), 0, stream,
                     (const int4*)dst, deg, E4);
  hipLaunchKernelGGL(alloc_rows_k, dim3((N + 255) / 256), dim3(256), 0, stream,
                     deg, rowstart, cursor, gcounter, N);
  hipLaunchKernelGGL(scatter_k, dim3((E4 + 255) / 256), dim3(256), 0, stream,
                     (const int4*)src, (const int4*)dst, cursor, src_sorted,
                     E4);
  // after scatter, cursor[i] == row end

  // ---- Layer 1: featb(sliced)[N,128] -> hb(sliced)[N,256] ----
  hipLaunchKernelGGL((gemm_mfma_k<16>), dim3(GX), dim3(256), 0, stream, featb,
                     wt1, hb, el, er, al1, ar1, N, 128);
  hipLaunchKernelGGL((node_agg4s_k<1>), dim3(NB4 * 8), dim3(256), 0, stream,
                     hb, el, er, rowstart, cursor, src_sorted, b1, fb, N);

  // ---- Layer 2: fb(sliced)[N,256] -> hb(sliced)[N,256] ----
  hipLaunchKernelGGL((gemm_mfma_k<16>), dim3(GX), dim3(256), 0, stream, fb,
                     wt2, hb, el, er, al2, ar2, N, 256);
  hipLaunchKernelGGL((node_agg4s_k<1>), dim3(NB4 * 8), dim3(256), 0, stream,
                     hb, el, er, rowstart, cursor, src_sorted, b2, fb, N);

  // ---- Layer 3: fb(sliced)[N,256] -> hb(sliced)[N,64] -> out fp32 ----
  hipLaunchKernelGGL((gemm_mfma_k<4>), dim3(GX), dim3(256), 0, stream, fb, wt3,
                     hb, el, er, al3, ar3, N, 256);
  hipLaunchKernelGGL(node_agg1s_k, dim3(NB4 * 2), dim3(256), 0, stream, hb, el,
                     er, rowstart, cursor, src_sorted, b3, out, N);
}

// Round 7
// 484.725 us; speedup vs baseline: 1.3863x; 1.3863x over previous
//
#include <hip/hip_runtime.h>
#include <math.h>

#define N_NODES 50000
#define N_EDGES 800000

typedef short bf8 __attribute__((ext_vector_type(8)));    // 8 bf16 (A/B frag)
typedef float f4x __attribute__((ext_vector_type(4)));    // C/D frag
typedef float f2v __attribute__((ext_vector_type(2)));    // packed fp32
typedef unsigned short us8 __attribute__((ext_vector_type(8)));  // 16B bf16

__device__ __forceinline__ unsigned short f2bf(float x) {
  unsigned u = __float_as_uint(x);
  unsigned r = (u + 0x7fff + ((u >> 16) & 1)) >> 16;  // RNE
  return (unsigned short)r;
}
__device__ __forceinline__ float bf2f(unsigned short b) {
  return __uint_as_float(((unsigned)b) << 16);
}
__device__ __forceinline__ f2v bfpair(unsigned d) {
  f2v r;
  r.x = __uint_as_float(d << 16);
  r.y = __uint_as_float(d & 0xffff0000u);
  return r;
}

// ---------------------------------------------------------------------------
// SLICED feature layout: tables stored [n_slices][N][32] bf16 (64B/row
// slice); gather blocks pin slice = bid & (NS-1). Round-robin block->XCD
// dispatch => each XCD's gather working set is one 3.2MB slice (fits 4MB
// private L2). R6 measured: FETCH 198->74MB (82% L2 hit). R7 removes R6's
// per-(node,slice) shfl-reduce overhead via quad-serial accumulation.
// ---------------------------------------------------------------------------

// One-shot conversions, single dispatch.
__device__ __forceinline__ void wt_cvt_one(const float* __restrict__ W,
                                           unsigned short* __restrict__ WT,
                                           int K, int M, int j) {
  int k8n = K >> 3;
  int m = j / k8n, k8 = j - m * k8n;
  us8 o;
#pragma unroll
  for (int r = 0; r < 8; ++r) o[r] = f2bf(W[(size_t)(k8 * 8 + r) * M + m]);
  *(us8*)(WT + (size_t)m * K + k8 * 8) = o;
}

__global__ __launch_bounds__(256) void cvt_all_k(
    const float* __restrict__ feat, unsigned short* __restrict__ featb,
    const float* __restrict__ W1, unsigned short* __restrict__ wt1,
    const float* __restrict__ W2, unsigned short* __restrict__ wt2,
    const float* __restrict__ W3, unsigned short* __restrict__ wt3) {
  const int F8 = N_NODES * 128 / 8;  // 800000
  int i = blockIdx.x * 256 + threadIdx.x;
  if (i < F8) {
    int n = i >> 4, c8 = i & 15;  // row, 8-col chunk
    float4 a = ((const float4*)feat)[2 * i];
    float4 b = ((const float4*)feat)[2 * i + 1];
    us8 o;
    o[0] = f2bf(a.x); o[1] = f2bf(a.y); o[2] = f2bf(a.z); o[3] = f2bf(a.w);
    o[4] = f2bf(b.x); o[5] = f2bf(b.y); o[6] = f2bf(b.z); o[7] = f2bf(b.w);
    // sliced: slice = c8>>2, in-slice offset (c8&3)*8
    *(us8*)(featb + ((size_t)(c8 >> 2) * N_NODES + n) * 32 + (c8 & 3) * 8) = o;
    return;
  }
  int j = i - F8;
  if (j < 4096) {                    // W1: 256 x 128
    wt_cvt_one(W1, wt1, 128, 256, j);
    return;
  }
  j -= 4096;
  if (j < 8192) {                    // W2: 256 x 256
    wt_cvt_one(W2, wt2, 256, 256, j);
    return;
  }
  j -= 8192;
  if (j < 2048) {                    // W3: 64 x 256
    wt_cvt_one(W3, wt3, 256, 64, j);
  }
}

// ---------------------------------------------------------------------------
// MFMA GEMM + fused el/er epilogue. Full-width output block (BN = M); A read
// once. A input and Y output both in SLICED [c][N][32] layout.
// BM=64, BK=32, 256 thr = 4 waves; wave owns 16-row stripe x M cols.
// ---------------------------------------------------------------------------
template <int NCT>
__global__ __launch_bounds__(256) void gemm_mfma_k(
    const unsigned short* __restrict__ Xb,
    const unsigned short* __restrict__ WT, unsigned short* __restrict__ Yb,
    float* __restrict__ el, float* __restrict__ er,
    const float* __restrict__ al, const float* __restrict__ ar, int N,
    int K) {
  const int H = NCT >> 2;  // heads (64 cols each)
  __shared__ unsigned short As[64][40];        // [m][k], +8 pad
  __shared__ unsigned short Bs[NCT * 16][40];  // [n][k], +8 pad
  const int tile_n = blockIdx.x * 64;
  const int t = threadIdx.x;
  const int wave = t >> 6, lane = t & 63;
  const int quad = lane >> 4, l16 = lane & 15;

  f4x acc[NCT];
#pragma unroll
  for (int ct = 0; ct < NCT; ++ct) acc[ct] = (f4x){0.f, 0.f, 0.f, 0.f};

  const int arow = t >> 2;         // A row 0..63
  const int akoff = (t & 3) * 8;   // A k-oct within 32-col slice

  for (int k0 = 0; k0 < K; k0 += 32) {
    {
      int gr = tile_n + arow;
      us8 a = (us8)0;
      if (gr < N)
        a = *(const us8*)(Xb + ((size_t)(k0 >> 5) * N + gr) * 32 + akoff);
      *(us8*)&As[arow][akoff] = a;
    }
#pragma unroll
    for (int u = 0; u < NCT / 4; ++u) {
      int g = t + u * 256;
      int brow = g >> 2, bk = (g & 3) * 8;
      *(us8*)&Bs[brow][bk] = *(const us8*)(WT + (size_t)brow * K + k0 + bk);
    }
    __syncthreads();
    bf8 afrag = *(const bf8*)&As[wave * 16 + l16][quad * 8];
#pragma unroll
    for (int ct = 0; ct < NCT; ++ct) {
      bf8 bfrag = *(const bf8*)&Bs[ct * 16 + l16][quad * 8];
      acc[ct] = __builtin_amdgcn_mfma_f32_16x16x32_bf16(afrag, bfrag, acc[ct],
                                                        0, 0, 0);
    }
    __syncthreads();
  }
  float al4[NCT], ar4[NCT];
#pragma unroll
  for (int ct = 0; ct < NCT; ++ct) {
    al4[ct] = al[ct * 16 + l16];
    ar4[ct] = ar[ct * 16 + l16];
  }
#pragma unroll
  for (int r = 0; r < 4; ++r) {
    int row = tile_n + wave * 16 + quad * 4 + r;
    float pl[H], pr[H];
#pragma unroll
    for (int h = 0; h < H; ++h) {
      pl[h] = 0.f;
      pr[h] = 0.f;
    }
#pragma unroll
    for (int ct = 0; ct < NCT; ++ct) {
      float y = acc[ct][r];
      pl[ct >> 2] += y * al4[ct];
      pr[ct >> 2] += y * ar4[ct];
      if (row < N)  // sliced write: slice ct>>1, in-slice col (ct&1)*16+l16
        Yb[((size_t)(ct >> 1) * N + row) * 32 + (ct & 1) * 16 + l16] = f2bf(y);
    }
#pragma unroll
    for (int off = 1; off < 16; off <<= 1)
#pragma unroll
      for (int h = 0; h < H; ++h) {
        pl[h] += __shfl_xor(pl[h], off);
        pr[h] += __shfl_xor(pr[h], off);
      }
    if (l16 == 0 && row < N) {
#pragma unroll
      for (int h = 0; h < H; ++h) {
        el[row * H + h] = pl[h];
        er[row * H + h] = pr[h];
      }
    }
  }
}

// ---------------------------------------------------------------------------
// CSR build (4 edges per thread, int4 loads)
// ---------------------------------------------------------------------------
__global__ __launch_bounds__(256) void count_deg_k(
    const int4* __restrict__ dst4, int* __restrict__ deg, int E4) {
  int i = blockIdx.x * blockDim.x + threadIdx.x;
  if (i < E4) {
    int4 d = dst4[i];
    atomicAdd(&deg[d.x], 1);
    atomicAdd(&deg[d.y], 1);
    atomicAdd(&deg[d.z], 1);
    atomicAdd(&deg[d.w], 1);
  }
}

__global__ __launch_bounds__(256) void alloc_rows_k(
    const int* __restrict__ deg, int* __restrict__ rowstart,
    int* __restrict__ cursor, int* __restrict__ gcounter, int N) {
  int i = blockIdx.x * blockDim.x + threadIdx.x;
  int lane = threadIdx.x & 63;
  int d = (i < N) ? deg[i] : 0;
  int x = d;
#pragma unroll
  for (int off = 1; off < 64; off <<= 1) {
    int t = __shfl_up(x, off);
    if (lane >= off) x += t;
  }
  int wsum = __shfl(x, 63);
  int base = 0;
  if (lane == 63) base = atomicAdd(gcounter, wsum);
  base = __shfl(base, 63);
  if (i < N) {
    int mystart = base + x - d;
    rowstart[i] = mystart;
    cursor[i] = mystart;
  }
}

__global__ __launch_bounds__(256) void scatter_k(
    const int4* __restrict__ src4, const int4* __restrict__ dst4,
    int* __restrict__ cursor, int* __restrict__ src_sorted, int E4) {
  int i = blockIdx.x * blockDim.x + threadIdx.x;
  if (i < E4) {
    int4 s = src4[i];
    int4 d = dst4[i];
    int p0 = atomicAdd(&cursor[d.x], 1);
    src_sorted[p0] = s.x;
    int p1 = atomicAdd(&cursor[d.y], 1);
    src_sorted[p1] = s.y;
    int p2 = atomicAdd(&cursor[d.z], 1);
    src_sorted[p2] = s.z;
    int p3 = atomicAdd(&cursor[d.w], 1);
    src_sorted[p3] = s.w;
  }
}

// ---------------------------------------------------------------------------
// QUAD-SERIAL XCD-sliced softmax+aggregation, H=4. One 4-lane quad per
// (node, slice): walks the CSR range serially, exp computed inline (el is
// L2-resident), lane-private accumulation of 8 cols each -> ZERO cross-lane
// reduces (R6's 4x VALU inflation). src prefetched one edge ahead so the
// 64B gather load issues first; exp overlaps its latency. 16 quads/wave =
// 16 gathers in flight per iteration.
// ---------------------------------------------------------------------------
template <int RELU>
__global__ __launch_bounds__(256) void node_agg4q_k(
    const unsigned short* __restrict__ hb, const float* __restrict__ el,
    const float* __restrict__ er, const int* __restrict__ rowstart,
    const int* __restrict__ rowend, const int* __restrict__ src_sorted,
    const float* __restrict__ bias, unsigned short* __restrict__ outb,
    int N) {
  const int slice = blockIdx.x & 7;
  const int node = (blockIdx.x >> 3) * 64 + (threadIdx.x >> 2);
  if (node >= N) return;
  const int flane = threadIdx.x & 3;
  const int head = slice >> 1;
  const unsigned short* hslice = hb + (size_t)slice * N * 32 + flane * 8;
  int start = rowstart[node], end = rowend[node];
  float er_v = er[node * 4 + head];
  f2v a0 = {0.f, 0.f}, a1 = {0.f, 0.f}, a2 = {0.f, 0.f}, a3 = {0.f, 0.f};
  float ssum = 0.f;
  int s_cur = (start < end) ? src_sorted[start] : 0;
  for (int p = start; p < end; ++p) {
    uint4 d = *(const uint4*)(hslice + (size_t)s_cur * 32);  // gather first
    int s_nxt = (p + 1 < end) ? src_sorted[p + 1] : 0;       // prefetch
    float e = el[s_cur * 4 + head] + er_v;                   // L2-hot
    e = (e >= 0.f) ? e : 0.2f * e;
    float ex = __expf(e);                                    // overlaps gather
    ssum += ex;
    f2v am = {ex, ex};
    a0 += bfpair(d.x) * am;
    a1 += bfpair(d.y) * am;
    a2 += bfpair(d.z) * am;
    a3 += bfpair(d.w) * am;
    s_cur = s_nxt;
  }
  float inv = (end > start) ? 1.f / ssum : 0.f;
  float accv[8] = {a0.x, a0.y, a1.x, a1.y, a2.x, a2.y, a3.x, a3.y};
  const float* bq = bias + slice * 32 + flane * 8;
  us8 o;
#pragma unroll
  for (int q = 0; q < 8; ++q) {
    float vv = accv[q] * inv + bq[q];
    if (RELU) vv = fmaxf(vv, 0.f);
    o[q] = f2bf(vv);
  }
  *(us8*)(outb + ((size_t)slice * N + node) * 32 + flane * 8) = o;
}

// H=1, F=64, fp32 out: 2 slices (even/odd XCDs each cache one 3.2MB slice).
__global__ __launch_bounds__(256) void node_agg1q_k(
    const unsigned short* __restrict__ hb, const float* __restrict__ el,
    const float* __restrict__ er, const int* __restrict__ rowstart,
    const int* __restrict__ rowend, const int* __restrict__ src_sorted,
    const float* __restrict__ bias, float* __restrict__ out, int N) {
  const int slice = blockIdx.x & 1;
  const int node = (blockIdx.x >> 1) * 64 + (threadIdx.x >> 2);
  if (node >= N) return;
  const int flane = threadIdx.x & 3;
  const unsigned short* hslice = hb + (size_t)slice * N * 32 + flane * 8;
  int start = rowstart[node], end = rowend[node];
  float er_v = er[node];
  f2v a0 = {0.f, 0.f}, a1 = {0.f, 0.f}, a2 = {0.f, 0.f}, a3 = {0.f, 0.f};
  float ssum = 0.f;
  int s_cur = (start < end) ? src_sorted[start] : 0;
  for (int p = start; p < end; ++p) {
    uint4 d = *(const uint4*)(hslice + (size_t)s_cur * 32);
    int s_nxt = (p + 1 < end) ? src_sorted[p + 1] : 0;
    float e = el[s_cur] + er_v;
    e = (e >= 0.f) ? e : 0.2f * e;
    float ex = __expf(e);
    ssum += ex;
    f2v am = {ex, ex};
    a0 += bfpair(d.x) * am;
    a1 += bfpair(d.y) * am;
    a2 += bfpair(d.z) * am;
    a3 += bfpair(d.w) * am;
    s_cur = s_nxt;
  }
  float inv = (end > start) ? 1.f / ssum : 0.f;
  float accv[8] = {a0.x, a0.y, a1.x, a1.y, a2.x, a2.y, a3.x, a3.y};
  const float* bq = bias + slice * 32 + flane * 8;
  float* o = out + (size_t)node * 64 + slice * 32 + flane * 8;
  float4 o0, o1;
  o0.x = accv[0] * inv + bq[0];
  o0.y = accv[1] * inv + bq[1];
  o0.z = accv[2] * inv + bq[2];
  o0.w = accv[3] * inv + bq[3];
  o1.x = accv[4] * inv + bq[4];
  o1.y = accv[5] * inv + bq[5];
  o1.z = accv[6] * inv + bq[6];
  o1.w = accv[7] * inv + bq[7];
  *(float4*)(o + 0) = o0;
  *(float4*)(o + 4) = o1;
}

// ---------------------------------------------------------------------------
extern "C" void kernel_launch(void* const* d_in, const int* in_sizes, int n_in,
                              void* d_out, int out_size, void* d_ws,
                              size_t ws_size, hipStream_t stream) {
  const float* feat = (const float*)d_in[0];
  const int* src = (const int*)d_in[1];
  const int* dst = (const int*)d_in[2];
  const float* W1 = (const float*)d_in[3];
  const float* al1 = (const float*)d_in[4];
  const float* ar1 = (const float*)d_in[5];
  const float* b1 = (const float*)d_in[6];
  const float* W2 = (const float*)d_in[7];
  const float* al2 = (const float*)d_in[8];
  const float* ar2 = (const float*)d_in[9];
  const float* b2 = (const float*)d_in[10];
  const float* W3 = (const float*)d_in[11];
  const float* al3 = (const float*)d_in[12];
  const float* ar3 = (const float*)d_in[13];
  const float* b3 = (const float*)d_in[14];
  float* out = (float*)d_out;

  unsigned short* hb = (unsigned short*)d_ws;             // [8][N][32] bf16
  unsigned short* fb = hb + (size_t)N_NODES * 256;        // [8][N][32] bf16
  float* el = (float*)(fb + (size_t)N_NODES * 256);       // N*4
  float* er = el + (size_t)N_NODES * 4;                   // N*4
  int* rowstart = (int*)(er + (size_t)N_NODES * 4);       // N
  int* cursor = rowstart + N_NODES;                       // N
  int* deg = cursor + N_NODES;                            // N
  int* gcounter = deg + N_NODES;                          // 1
  int* src_sorted = gcounter + 1;                         // E
  unsigned short* wt1 = (unsigned short*)(src_sorted + N_EDGES);  // 256*128
  unsigned short* wt2 = wt1 + 256 * 128;                  // 256*256
  unsigned short* wt3 = wt2 + 256 * 256;                  // 64*256
  // featb (sliced bf16 feat) aliases fb: GEMM1 consumes it before agg writes.
  unsigned short* featb = fb;

  const int N = N_NODES, E = N_EDGES;
  const int E4 = E / 4;
  const int GX = (N + 63) / 64;   // 782
  const int NB64 = (N + 63) / 64; // node-groups of 64 (one per quad)

  // ---- one-shot conversions (single dispatch) ----
  const int CVT_TOTAL = N * 128 / 8 + 4096 + 8192 + 2048;
  hipLaunchKernelGGL(cvt_all_k, dim3((CVT_TOTAL + 255) / 256), dim3(256), 0,
                     stream, feat, featb, W1, wt1, W2, wt2, W3, wt3);

  // ---- CSR build ----
  hipMemsetAsync(deg, 0, (size_t)(N + 1) * sizeof(int), stream);
  hipLaunchKernelGGL(count_deg_k, dim3((E4 + 255) / 256), dim3(256), 0, stream,
                     (const int4*)dst, deg, E4);
  hipLaunchKernelGGL(alloc_rows_k, dim3((N + 255) / 256), dim3(256), 0, stream,
                     deg, rowstart, cursor, gcounter, N);
  hipLaunchKernelGGL(scatter_k, dim3((E4 + 255) / 256), dim3(256), 0, stream,
                     (const int4*)src, (const int4*)dst, cursor, src_sorted,
                     E4);
  // after scatter, cursor[i] == row end

  // ---- Layer 1: featb(sliced)[N,128] -> hb(sliced)[N,256] ----
  hipLaunchKernelGGL((gemm_mfma_k<16>), dim3(GX), dim3(256), 0, stream, featb,
                     wt1, hb, el, er, al1, ar1, N, 128);
  hipLaunchKernelGGL((node_agg4q_k<1>), dim3(NB64 * 8), dim3(256), 0, stream,
                     hb, el, er, rowstart, cursor, src_sorted, b1, fb, N);

  // ---- Layer 2: fb(sliced)[N,256] -> hb(sliced)[N,256] ----
  hipLaunchKernelGGL((gemm_mfma_k<16>), dim3(GX), dim3(256), 0, stream, fb,
                     wt2, hb, el, er, al2, ar2, N, 256);
  hipLaunchKernelGGL((node_agg4q_k<1>), dim3(NB64 * 8), dim3(256), 0, stream,
                     hb, el, er, rowstart, cursor, src_sorted, b2, fb, N);

  // ---- Layer 3: fb(sliced)[N,256] -> hb(sliced)[N,64] -> out fp32 ----
  hipLaunchKernelGGL((gemm_mfma_k<4>), dim3(GX), dim3(256), 0, stream, fb, wt3,
                     hb, el, er, al3, ar3, N, 256);
  hipLaunchKernelGGL(node_agg1q_k, dim3(NB64 * 2), dim3(256), 0, stream, hb,
                     el, er, rowstart, cursor, src_sorted, b3, out, N);
}

// Round 8
// 415.420 us; speedup vs baseline: 1.6176x; 1.1668x over previous
//
#include <hip/hip_runtime.h>
#include <math.h>

#define N_NODES 50000
#define N_EDGES 800000

typedef short bf8 __attribute__((ext_vector_type(8)));    // 8 bf16 (A/B frag)
typedef float f4x __attribute__((ext_vector_type(4)));    // C/D frag
typedef float f2v __attribute__((ext_vector_type(2)));    // packed fp32
typedef unsigned short us8 __attribute__((ext_vector_type(8)));  // 16B bf16

__device__ __forceinline__ unsigned short f2bf(float x) {
  unsigned u = __float_as_uint(x);
  unsigned r = (u + 0x7fff + ((u >> 16) & 1)) >> 16;  // RNE
  return (unsigned short)r;
}
__device__ __forceinline__ float bf2f(unsigned short b) {
  return __uint_as_float(((unsigned)b) << 16);
}
__device__ __forceinline__ f2v bfpair(unsigned d) {
  f2v r;
  r.x = __uint_as_float(d << 16);
  r.y = __uint_as_float(d & 0xffff0000u);
  return r;
}

// ---------------------------------------------------------------------------
// One-shot conversions + degree count, single dispatch (regions):
//   0: feat fp32 -> bf16 row-major [N][128]
//   1-3: W[K][M] fp32 -> WT[M][K] bf16 (transpose)
//   4: count_deg (int4 dst, 4 edges/thread) — deg memset'd beforehand
// ---------------------------------------------------------------------------
__device__ __forceinline__ void wt_cvt_one(const float* __restrict__ W,
                                           unsigned short* __restrict__ WT,
                                           int K, int M, int j) {
  int k8n = K >> 3;
  int m = j / k8n, k8 = j - m * k8n;
  us8 o;
#pragma unroll
  for (int r = 0; r < 8; ++r) o[r] = f2bf(W[(size_t)(k8 * 8 + r) * M + m]);
  *(us8*)(WT + (size_t)m * K + k8 * 8) = o;
}

__global__ __launch_bounds__(256) void cvt_all_k(
    const float* __restrict__ feat, unsigned short* __restrict__ featb,
    const float* __restrict__ W1, unsigned short* __restrict__ wt1,
    const float* __restrict__ W2, unsigned short* __restrict__ wt2,
    const float* __restrict__ W3, unsigned short* __restrict__ wt3,
    const int4* __restrict__ dst4, int* __restrict__ deg, int E4) {
  const int F8 = N_NODES * 128 / 8;  // 800000
  int i = blockIdx.x * 256 + threadIdx.x;
  if (i < F8) {
    float4 a = ((const float4*)feat)[2 * i];
    float4 b = ((const float4*)feat)[2 * i + 1];
    us8 o;
    o[0] = f2bf(a.x); o[1] = f2bf(a.y); o[2] = f2bf(a.z); o[3] = f2bf(a.w);
    o[4] = f2bf(b.x); o[5] = f2bf(b.y); o[6] = f2bf(b.z); o[7] = f2bf(b.w);
    ((us8*)featb)[i] = o;  // row-major contiguous
    return;
  }
  int j = i - F8;
  if (j < 4096) {  // W1: 128x256
    wt_cvt_one(W1, wt1, 128, 256, j);
    return;
  }
  j -= 4096;
  if (j < 8192) {  // W2: 256x256
    wt_cvt_one(W2, wt2, 256, 256, j);
    return;
  }
  j -= 8192;
  if (j < 2048) {  // W3: 256x64
    wt_cvt_one(W3, wt3, 256, 64, j);
    return;
  }
  j -= 2048;
  if (j < E4) {  // count_deg
    int4 d = dst4[j];
    atomicAdd(&deg[d.x], 1);
    atomicAdd(&deg[d.y], 1);
    atomicAdd(&deg[d.z], 1);
    atomicAdd(&deg[d.w], 1);
  }
}

// ---------------------------------------------------------------------------
// MFMA GEMM + fused el/er epilogue. Full-width output block (BN = M): A read
// from HBM exactly once. Row-major Xb [N][K] and Yb [N][M].
// BM=64, BK=32, 256 thr = 4 waves; wave owns a 16-row stripe x M cols.
// ---------------------------------------------------------------------------
template <int NCT>
__global__ __launch_bounds__(256) void gemm_mfma_k(
    const unsigned short* __restrict__ Xb,
    const unsigned short* __restrict__ WT, unsigned short* __restrict__ Yb,
    float* __restrict__ el, float* __restrict__ er,
    const float* __restrict__ al, const float* __restrict__ ar, int N,
    int K) {
  const int M = NCT * 16;
  const int H = NCT >> 2;  // heads (64 cols each)
  __shared__ unsigned short As[64][40];        // [m][k], +8 pad
  __shared__ unsigned short Bs[NCT * 16][40];  // [n][k], +8 pad
  const int tile_n = blockIdx.x * 64;
  const int t = threadIdx.x;
  const int wave = t >> 6, lane = t & 63;
  const int quad = lane >> 4, l16 = lane & 15;

  f4x acc[NCT];
#pragma unroll
  for (int ct = 0; ct < NCT; ++ct) acc[ct] = (f4x){0.f, 0.f, 0.f, 0.f};

  const int arow = t >> 2;        // A row 0..63
  const int akoff = (t & 3) * 8;  // A k-oct

  for (int k0 = 0; k0 < K; k0 += 32) {
    {
      int gr = tile_n + arow;
      us8 a = (us8)0;
      if (gr < N) a = *(const us8*)(Xb + (size_t)gr * K + k0 + akoff);
      *(us8*)&As[arow][akoff] = a;
    }
#pragma unroll
    for (int u = 0; u < NCT / 4; ++u) {
      int g = t + u * 256;
      int brow = g >> 2, bk = (g & 3) * 8;
      *(us8*)&Bs[brow][bk] = *(const us8*)(WT + (size_t)brow * K + k0 + bk);
    }
    __syncthreads();
    bf8 afrag = *(const bf8*)&As[wave * 16 + l16][quad * 8];
#pragma unroll
    for (int ct = 0; ct < NCT; ++ct) {
      bf8 bfrag = *(const bf8*)&Bs[ct * 16 + l16][quad * 8];
      acc[ct] = __builtin_amdgcn_mfma_f32_16x16x32_bf16(afrag, bfrag, acc[ct],
                                                        0, 0, 0);
    }
    __syncthreads();
  }
  float al4[NCT], ar4[NCT];
#pragma unroll
  for (int ct = 0; ct < NCT; ++ct) {
    al4[ct] = al[ct * 16 + l16];
    ar4[ct] = ar[ct * 16 + l16];
  }
#pragma unroll
  for (int r = 0; r < 4; ++r) {
    int row = tile_n + wave * 16 + quad * 4 + r;
    float pl[H], pr[H];
#pragma unroll
    for (int h = 0; h < H; ++h) {
      pl[h] = 0.f;
      pr[h] = 0.f;
    }
#pragma unroll
    for (int ct = 0; ct < NCT; ++ct) {
      float y = acc[ct][r];
      pl[ct >> 2] += y * al4[ct];
      pr[ct >> 2] += y * ar4[ct];
      if (row < N) Yb[(size_t)row * M + ct * 16 + l16] = f2bf(y);
    }
#pragma unroll
    for (int off = 1; off < 16; off <<= 1)
#pragma unroll
      for (int h = 0; h < H; ++h) {
        pl[h] += __shfl_xor(pl[h], off);
        pr[h] += __shfl_xor(pr[h], off);
      }
    if (l16 == 0 && row < N) {
#pragma unroll
      for (int h = 0; h < H; ++h) {
        el[row * H + h] = pl[h];
        er[row * H + h] = pr[h];
      }
    }
  }
}

// ---------------------------------------------------------------------------
// CSR build: prefix-scan row allocation + scatter (count folded into cvt_all)
// ---------------------------------------------------------------------------
__global__ __launch_bounds__(256) void alloc_rows_k(
    const int* __restrict__ deg, int* __restrict__ rowstart,
    int* __restrict__ cursor, int* __restrict__ gcounter, int N) {
  int i = blockIdx.x * blockDim.x + threadIdx.x;
  int lane = threadIdx.x & 63;
  int d = (i < N) ? deg[i] : 0;
  int x = d;
#pragma unroll
  for (int off = 1; off < 64; off <<= 1) {
    int t = __shfl_up(x, off);
    if (lane >= off) x += t;
  }
  int wsum = __shfl(x, 63);
  int base = 0;
  if (lane == 63) base = atomicAdd(gcounter, wsum);
  base = __shfl(base, 63);
  if (i < N) {
    int mystart = base + x - d;
    rowstart[i] = mystart;
    cursor[i] = mystart;
  }
}

__global__ __launch_bounds__(256) void scatter_k(
    const int4* __restrict__ src4, const int4* __restrict__ dst4,
    int* __restrict__ cursor, int* __restrict__ src_sorted, int E4) {
  int i = blockIdx.x * blockDim.x + threadIdx.x;
  if (i < E4) {
    int4 s = src4[i];
    int4 d = dst4[i];
    int p0 = atomicAdd(&cursor[d.x], 1);
    src_sorted[p0] = s.x;
    int p1 = atomicAdd(&cursor[d.y], 1);
    src_sorted[p1] = s.y;
    int p2 = atomicAdd(&cursor[d.z], 1);
    src_sorted[p2] = s.z;
    int p3 = atomicAdd(&cursor[d.w], 1);
    src_sorted[p3] = s.w;
  }
}

// ---------------------------------------------------------------------------
// Fused single-pass softmax+aggregation, H=4, F=64. One wave per dst node.
// R2 structure (best measured: 65us) + BATCHED phase-B gathers: 4 uint4
// loads issue back-to-back into named regs before any FMA -> 2x gathers in
// flight per wave (R2 had 2). Invalid slots already resolve to row-0/alpha=0
// so batches need no per-slot branches (one wave-uniform nj>4 check).
// ---------------------------------------------------------------------------
template <int RELU>
__global__ __launch_bounds__(256) void node_agg4_k(
    const unsigned short* __restrict__ hb, const float* __restrict__ el,
    const float* __restrict__ er, const int* __restrict__ rowstart,
    const int* __restrict__ rowend, const int* __restrict__ src_sorted,
    const float* __restrict__ bias, unsigned short* __restrict__ outb,
    int N) {
  int node = blockIdx.x * 4 + (threadIdx.x >> 6);
  int lane = threadIdx.x & 63;
  if (node >= N) return;
  int start = rowstart[node], end = rowend[node];
  int e16 = lane & 15;     // phase-A edge within chunk
  int headA = lane >> 4;   // phase-A head
  int eslot = lane >> 5;   // phase-B edge parity (batch-of-4 in flight)
  int flane = lane & 31;   // phase-B feature lane (32 x 8 bf16 = 256 feat)
  int fo8 = flane << 3;
  int headf = fo8 >> 6;    // head owning my features
  float er_a = er[node * 4 + headA];
  f2v acc2[4];
#pragma unroll
  for (int q = 0; q < 4; ++q) acc2[q] = (f2v){0.f, 0.f};
  float ssum = 0.f;  // per-(edge,head) partial; head = headA on this lane
  for (int c0 = start; c0 < end; c0 += 16) {
    // ---- phase A: 16 edges x 4 heads, wave-wide ----
    int p = c0 + e16;
    bool v = p < end;
    int s = v ? src_sorted[p] : 0;  // row 0 stays cache-hot for tail
    float e = el[s * 4 + headA] + er_a;
    e = (e >= 0.f) ? e : 0.2f * e;
    float ex = v ? __expf(e) : 0.f;
    ssum += ex;
    // ---- distribute to consumer lanes (register traffic only) ----
    int sjv[8];
    float ajv[8];
#pragma unroll
    for (int jj = 0; jj < 8; ++jj) {
      int idx = (2 * jj + eslot) | (headf << 4);
      sjv[jj] = __shfl(s, idx);   // src of edge (2*jj+eslot); 0 if invalid
      ajv[jj] = __shfl(ex, idx);  // its alpha-numer for my head; 0 if invalid
    }
    int nch = end - c0;
    if (nch > 16) nch = 16;
    int nj = (nch + 1) >> 1;  // wave-uniform, 1..8
    // ---- phase B batch 1: 4 gathers issue back-to-back, then consume ----
    uint4 d0 = *(const uint4*)(hb + (size_t)sjv[0] * 256 + fo8);
    uint4 d1 = *(const uint4*)(hb + (size_t)sjv[1] * 256 + fo8);
    uint4 d2 = *(const uint4*)(hb + (size_t)sjv[2] * 256 + fo8);
    uint4 d3 = *(const uint4*)(hb + (size_t)sjv[3] * 256 + fo8);
    {
      f2v a0 = {ajv[0], ajv[0]}, a1 = {ajv[1], ajv[1]};
      f2v a2 = {ajv[2], ajv[2]}, a3 = {ajv[3], ajv[3]};
      acc2[0] += bfpair(d0.x) * a0;
      acc2[1] += bfpair(d0.y) * a0;
      acc2[2] += bfpair(d0.z) * a0;
      acc2[3] += bfpair(d0.w) * a0;
      acc2[0] += bfpair(d1.x) * a1;
      acc2[1] += bfpair(d1.y) * a1;
      acc2[2] += bfpair(d1.z) * a1;
      acc2[3] += bfpair(d1.w) * a1;
      acc2[0] += bfpair(d2.x) * a2;
      acc2[1] += bfpair(d2.y) * a2;
      acc2[2] += bfpair(d2.z) * a2;
      acc2[3] += bfpair(d2.w) * a2;
      acc2[0] += bfpair(d3.x) * a3;
      acc2[1] += bfpair(d3.y) * a3;
      acc2[2] += bfpair(d3.z) * a3;
      acc2[3] += bfpair(d3.w) * a3;
    }
    if (nj > 4) {  // wave-uniform
      uint4 e0 = *(const uint4*)(hb + (size_t)sjv[4] * 256 + fo8);
      uint4 e1 = *(const uint4*)(hb + (size_t)sjv[5] * 256 + fo8);
      uint4 e2 = *(const uint4*)(hb + (size_t)sjv[6] * 256 + fo8);
      uint4 e3 = *(const uint4*)(hb + (size_t)sjv[7] * 256 + fo8);
      f2v a0 = {ajv[4], ajv[4]}, a1 = {ajv[5], ajv[5]};
      f2v a2 = {ajv[6], ajv[6]}, a3 = {ajv[7], ajv[7]};
      acc2[0] += bfpair(e0.x) * a0;
      acc2[1] += bfpair(e0.y) * a0;
      acc2[2] += bfpair(e0.z) * a0;
      acc2[3] += bfpair(e0.w) * a0;
      acc2[0] += bfpair(e1.x) * a1;
      acc2[1] += bfpair(e1.y) * a1;
      acc2[2] += bfpair(e1.z) * a1;
      acc2[3] += bfpair(e1.w) * a1;
      acc2[0] += bfpair(e2.x) * a2;
      acc2[1] += bfpair(e2.y) * a2;
      acc2[2] += bfpair(e2.z) * a2;
      acc2[3] += bfpair(e2.w) * a2;
      acc2[0] += bfpair(e3.x) * a3;
      acc2[1] += bfpair(e3.y) * a3;
      acc2[2] += bfpair(e3.z) * a3;
      acc2[3] += bfpair(e3.w) * a3;
    }
  }
  // per-head denominator: reduce within each 16-lane head group
#pragma unroll
  for (int off = 1; off < 16; off <<= 1) ssum += __shfl_xor(ssum, off);
  float sden = __shfl(ssum, headf << 4);  // total for my output head
  float acc[8];
#pragma unroll
  for (int q = 0; q < 4; ++q) {
    acc[2 * q] = acc2[q].x;
    acc[2 * q + 1] = acc2[q].y;
  }
  // combine the two edge slots (lane f <-> lane f+32: same flane/headf)
#pragma unroll
  for (int q = 0; q < 8; ++q) acc[q] += __shfl_xor(acc[q], 32);
  float inv = (end > start) ? 1.f / sden : 0.f;
  if (eslot == 0) {
    us8 o;
#pragma unroll
    for (int q = 0; q < 8; ++q) {
      float vv = acc[q] * inv + bias[fo8 + q];
      if (RELU) vv = fmaxf(vv, 0.f);
      o[q] = f2bf(vv);
    }
    *(us8*)(outb + (size_t)node * 256 + fo8) = o;
  }
}

// H=1, F=64: 64-edge phase A; phase B 8 eslots x 8 flanes (16B each),
// batched 4 gathers before consuming.
__global__ __launch_bounds__(256) void node_agg1_k(
    const unsigned short* __restrict__ hb, const float* __restrict__ el,
    const float* __restrict__ er, const int* __restrict__ rowstart,
    const int* __restrict__ rowend, const int* __restrict__ src_sorted,
    const float* __restrict__ bias, float* __restrict__ out, int N) {
  int node = blockIdx.x * 4 + (threadIdx.x >> 6);
  int lane = threadIdx.x & 63;
  if (node >= N) return;
  int start = rowstart[node], end = rowend[node];
  int eslot = lane >> 3;
  int fo8 = (lane & 7) << 3;
  float er_v = er[node];
  f2v acc2[4];
#pragma unroll
  for (int q = 0; q < 4; ++q) acc2[q] = (f2v){0.f, 0.f};
  float ssum = 0.f;
  for (int c0 = start; c0 < end; c0 += 64) {
    // phase A: 64 edges wave-wide
    int p = c0 + lane;
    bool v = p < end;
    int s = v ? src_sorted[p] : 0;
    float e = el[s] + er_v;
    e = (e >= 0.f) ? e : 0.2f * e;
    float ex = v ? __expf(e) : 0.f;
    ssum += ex;
    int nch = end - c0;
    if (nch > 64) nch = 64;
    int nj = (nch + 7) >> 3;  // wave-uniform, 1..8
    // phase B, batches of 4 (invalid slots: s=0, a=0 — harmless)
    {
      int s0 = __shfl(s, 0 * 8 + eslot), s1 = __shfl(s, 1 * 8 + eslot);
      int s2 = __shfl(s, 2 * 8 + eslot), s3 = __shfl(s, 3 * 8 + eslot);
      float b0 = __shfl(ex, 0 * 8 + eslot), b1 = __shfl(ex, 1 * 8 + eslot);
      float b2 = __shfl(ex, 2 * 8 + eslot), b3 = __shfl(ex, 3 * 8 + eslot);
      uint4 d0 = *(const uint4*)(hb + (size_t)s0 * 64 + fo8);
      uint4 d1 = *(const uint4*)(hb + (size_t)s1 * 64 + fo8);
      uint4 d2 = *(const uint4*)(hb + (size_t)s2 * 64 + fo8);
      uint4 d3 = *(const uint4*)(hb + (size_t)s3 * 64 + fo8);
      f2v a0 = {b0, b0}, a1 = {b1, b1}, a2 = {b2, b2}, a3 = {b3, b3};
      acc2[0] += bfpair(d0.x) * a0;
      acc2[1] += bfpair(d0.y) * a0;
      acc2[2] += bfpair(d0.z) * a0;
      acc2[3] += bfpair(d0.w) * a0;
      acc2[0] += bfpair(d1.x) * a1;
      acc2[1] += bfpair(d1.y) * a1;
      acc2[2] += bfpair(d1.z) * a1;
      acc2[3] += bfpair(d1.w) * a1;
      acc2[0] += bfpair(d2.x) * a2;
      acc2[1] += bfpair(d2.y) * a2;
      acc2[2] += bfpair(d2.z) * a2;
      acc2[3] += bfpair(d2.w) * a2;
      acc2[0] += bfpair(d3.x) * a3;
      acc2[1] += bfpair(d3.y) * a3;
      acc2[2] += bfpair(d3.z) * a3;
      acc2[3] += bfpair(d3.w) * a3;
    }
    if (nj > 4) {
      int s0 = __shfl(s, 4 * 8 + eslot), s1 = __shfl(s, 5 * 8 + eslot);
      int s2 = __shfl(s, 6 * 8 + eslot), s3 = __shfl(s, 7 * 8 + eslot);
      float b0 = __shfl(ex, 4 * 8 + eslot), b1 = __shfl(ex, 5 * 8 + eslot);
      float b2 = __shfl(ex, 6 * 8 + eslot), b3 = __shfl(ex, 7 * 8 + eslot);
      uint4 d0 = *(const uint4*)(hb + (size_t)s0 * 64 + fo8);
      uint4 d1 = *(const uint4*)(hb + (size_t)s1 * 64 + fo8);
      uint4 d2 = *(const uint4*)(hb + (size_t)s2 * 64 + fo8);
      uint4 d3 = *(const uint4*)(hb + (size_t)s3 * 64 + fo8);
      f2v a0 = {b0, b0}, a1 = {b1, b1}, a2 = {b2, b2}, a3 = {b3, b3};
      acc2[0] += bfpair(d0.x) * a0;
      acc2[1] += bfpair(d0.y) * a0;
      acc2[2] += bfpair(d0.z) * a0;
      acc2[3] += bfpair(d0.w) * a0;
      acc2[0] += bfpair(d1.x) * a1;
      acc2[1] += bfpair(d1.y) * a1;
      acc2[2] += bfpair(d1.z) * a1;
      acc2[3] += bfpair(d1.w) * a1;
      acc2[0] += bfpair(d2.x) * a2;
      acc2[1] += bfpair(d2.y) * a2;
      acc2[2] += bfpair(d2.z) * a2;
      acc2[3] += bfpair(d2.w) * a2;
      acc2[0] += bfpair(d3.x) * a3;
      acc2[1] += bfpair(d3.y) * a3;
      acc2[2] += bfpair(d3.z) * a3;
      acc2[3] += bfpair(d3.w) * a3;
    }
  }
#pragma unroll
  for (int off = 1; off < 64; off <<= 1) ssum += __shfl_xor(ssum, off);
  float acc[8];
#pragma unroll
  for (int q = 0; q < 4; ++q) {
    acc[2 * q] = acc2[q].x;
    acc[2 * q + 1] = acc2[q].y;
  }
  // combine the 8 edge slots (xor 8/16/32 preserves feature lane)
#pragma unroll
  for (int off = 8; off < 64; off <<= 1)
#pragma unroll
    for (int q = 0; q < 8; ++q) acc[q] += __shfl_xor(acc[q], off);
  float inv = (end > start) ? 1.f / ssum : 0.f;
  if (eslot == 0) {
    float* o = out + (size_t)node * 64 + fo8;
#pragma unroll
    for (int q = 0; q < 8; ++q) o[q] = acc[q] * inv + bias[fo8 + q];
  }
}

// ---------------------------------------------------------------------------
extern "C" void kernel_launch(void* const* d_in, const int* in_sizes, int n_in,
                              void* d_out, int out_size, void* d_ws,
                              size_t ws_size, hipStream_t stream) {
  const float* feat = (const float*)d_in[0];
  const int* src = (const int*)d_in[1];
  const int* dst = (const int*)d_in[2];
  const float* W1 = (const float*)d_in[3];
  const float* al1 = (const float*)d_in[4];
  const float* ar1 = (const float*)d_in[5];
  const float* b1 = (const float*)d_in[6];
  const float* W2 = (const float*)d_in[7];
  const float* al2 = (const float*)d_in[8];
  const float* ar2 = (const float*)d_in[9];
  const float* b2 = (const float*)d_in[10];
  const float* W3 = (const float*)d_in[11];
  const float* al3 = (const float*)d_in[12];
  const float* ar3 = (const float*)d_in[13];
  const float* b3 = (const float*)d_in[14];
  float* out = (float*)d_out;

  unsigned short* hb = (unsigned short*)d_ws;             // N*256 bf16
  unsigned short* fb = hb + (size_t)N_NODES * 256;        // N*256 bf16
  float* el = (float*)(fb + (size_t)N_NODES * 256);       // N*4
  float* er = el + (size_t)N_NODES * 4;                   // N*4
  int* rowstart = (int*)(er + (size_t)N_NODES * 4);       // N
  int* cursor = rowstart + N_NODES;                       // N
  int* deg = cursor + N_NODES;                            // N
  int* gcounter = deg + N_NODES;                          // 1
  int* src_sorted = gcounter + 1;                         // E
  unsigned short* wt1 = (unsigned short*)(src_sorted + N_EDGES);  // 256*128
  unsigned short* wt2 = wt1 + 256 * 128;                  // 256*256
  unsigned short* wt3 = wt2 + 256 * 256;                  // 64*256
  // featb (bf16 feat) aliases fb: GEMM1 consumes it before agg writes fb.
  unsigned short* featb = fb;

  const int N = N_NODES, E = N_EDGES;
  const int E4 = E / 4;
  const int GX = (N + 63) / 64;  // 782

  // ---- deg zero, then fused conversions + count_deg (one dispatch) ----
  hipMemsetAsync(deg, 0, (size_t)(N + 1) * sizeof(int), stream);
  const int CVT_TOTAL = N * 128 / 8 + 4096 + 8192 + 2048 + E4;
  hipLaunchKernelGGL(cvt_all_k, dim3((CVT_TOTAL + 255) / 256), dim3(256), 0,
                     stream, feat, featb, W1, wt1, W2, wt2, W3, wt3,
                     (const int4*)dst, deg, E4);

  // ---- CSR build ----
  hipLaunchKernelGGL(alloc_rows_k, dim3((N + 255) / 256), dim3(256), 0, stream,
                     deg, rowstart, cursor, gcounter, N);
  hipLaunchKernelGGL(scatter_k, dim3((E4 + 255) / 256), dim3(256), 0, stream,
                     (const int4*)src, (const int4*)dst, cursor, src_sorted,
                     E4);
  // after scatter, cursor[i] == row end

  // ---- Layer 1: featb[N,128] -> hb[N,256] (bf16) ----
  hipLaunchKernelGGL((gemm_mfma_k<16>), dim3(GX), dim3(256), 0, stream, featb,
                     wt1, hb, el, er, al1, ar1, N, 128);
  hipLaunchKernelGGL((node_agg4_k<1>), dim3((N + 3) / 4), dim3(256), 0, stream,
                     hb, el, er, rowstart, cursor, src_sorted, b1, fb, N);

  // ---- Layer 2: fb[N,256] -> hb[N,256] (bf16) ----
  hipLaunchKernelGGL((gemm_mfma_k<16>), dim3(GX), dim3(256), 0, stream, fb,
                     wt2, hb, el, er, al2, ar2, N, 256);
  hipLaunchKernelGGL((node_agg4_k<1>), dim3((N + 3) / 4), dim3(256), 0, stream,
                     hb, el, er, rowstart, cursor, src_sorted, b2, fb, N);

  // ---- Layer 3: fb[N,256] -> hb[N,64] (bf16) -> out fp32 ----
  hipLaunchKernelGGL((gemm_mfma_k<4>), dim3(GX), dim3(256), 0, stream, fb, wt3,
                     hb, el, er, al3, ar3, N, 256);
  hipLaunchKernelGGL(node_agg1_k, dim3((N + 3) / 4), dim3(256), 0, stream, hb,
                     el, er, rowstart, cursor, src_sorted, b3, out, N);
}